// Round 1
// baseline (16098.434 us; speedup 1.0000x reference)
//
#include <hip/hip_runtime.h>
#include <math.h>

#define E_ 7
#define B_ 50
#define T_ 100
#define D_ 128
#define A_ 32
#define L_ 256
#define H_ 1024
#define C_ 128
#define LAD_ 416
#define EB_ 350
#define TB_ 5000
#define SQRTH 0.31622776601683794f

struct G8 {
  const float* A[8];
  const float* W[8];
  const float* b[8];
  float* C[8];
};

// Generic tiled fp32 GEMM: C[bz] = ACT(A[bz] @ W[bz] + b[bz])
// BM=BN=64, BK=16, 256 threads, 4x4 per thread. N must be a multiple of 64
// (grid.y covers it exactly); K must be a multiple of 16; M guarded.
template<int ACT>
__global__ __launch_bounds__(256)
void gemm64(G8 g, int M, int K, int lda, int ldw, int ldc) {
  __shared__ float As[16][68];  // transposed [k][m], pad to 68
  __shared__ float Bs[16][64];
  const int tid = threadIdx.x;
  const float* __restrict__ A = g.A[blockIdx.z];
  const float* __restrict__ W = g.W[blockIdx.z];
  const float* __restrict__ bias = g.b[blockIdx.z];
  float* __restrict__ C = g.C[blockIdx.z];
  const int bm = blockIdx.x * 64;
  const int bn = blockIdx.y * 64;
  const int tm = (tid >> 4) << 2;
  const int tn = (tid & 15) << 2;
  const int am = tid >> 2;          // 0..63
  const int ak = (tid & 3) << 2;    // 0,4,8,12
  const int bk = tid >> 4;          // 0..15
  const int bn4 = (tid & 15) << 2;  // 0..60
  float acc[4][4] = {};
  for (int k0 = 0; k0 < K; k0 += 16) {
    float4 av = make_float4(0.f, 0.f, 0.f, 0.f);
    if (bm + am < M) av = *(const float4*)(A + (size_t)(bm + am) * lda + (k0 + ak));
    const float4 wv = *(const float4*)(W + (size_t)(k0 + bk) * ldw + (bn + bn4));
    __syncthreads();
    As[ak + 0][am] = av.x; As[ak + 1][am] = av.y;
    As[ak + 2][am] = av.z; As[ak + 3][am] = av.w;
    *(float4*)&Bs[bk][bn4] = wv;
    __syncthreads();
#pragma unroll
    for (int k = 0; k < 16; ++k) {
      const float4 a4 = *(const float4*)&As[k][tm];
      const float4 b4 = *(const float4*)&Bs[k][tn];
      const float ar[4] = {a4.x, a4.y, a4.z, a4.w};
      const float br[4] = {b4.x, b4.y, b4.z, b4.w};
#pragma unroll
      for (int i = 0; i < 4; ++i)
#pragma unroll
        for (int j = 0; j < 4; ++j)
          acc[i][j] = fmaf(ar[i], br[j], acc[i][j]);
    }
  }
#pragma unroll
  for (int i = 0; i < 4; ++i) {
    const int m = bm + tm + i;
    if (m < M) {
#pragma unroll
      for (int j = 0; j < 4; ++j) {
        float v = acc[i][j];
        if (bias) v += bias[bn + tn + j];
        if (ACT == 1) v = fmaxf(v, 0.f);
        if (ACT == 2) v = tanhf(v);
        C[(size_t)m * ldc + (bn + tn + j)] = v;
      }
    }
  }
}

// z = concat(z_in, a_t, x_t) @ act_w[e] + act_b[e]   (per-e, M=50, K=416, N=256)
// grid (N/64=4, E)
__global__ __launch_bounds__(256)
void act_gemm(const float* __restrict__ zin, int zin_estride,
              const float* __restrict__ actions, const float* __restrict__ xs,
              const float* __restrict__ act_w, const float* __restrict__ act_b,
              float* __restrict__ zout, int t) {
  __shared__ float As[16][68];
  __shared__ float Bs[16][64];
  const int tid = threadIdx.x;
  const int e = blockIdx.y;
  const int bn = blockIdx.x * 64;
  const int tm = (tid >> 4) << 2;
  const int tn = (tid & 15) << 2;
  const int am = tid >> 2;
  const int ak = (tid & 3) << 2;
  const int bk = tid >> 4;
  const int bn4 = (tid & 15) << 2;
  const float* W = act_w + (size_t)e * LAD_ * L_;
  const float* zin_e = zin + (size_t)e * zin_estride;
  float acc[4][4] = {};
  for (int k0 = 0; k0 < LAD_; k0 += 16) {
    float4 av = make_float4(0.f, 0.f, 0.f, 0.f);
    const int k = k0 + ak;
    if (am < B_) {
      if (k < L_)
        av = *(const float4*)(zin_e + (size_t)am * L_ + k);
      else if (k < L_ + A_)
        av = *(const float4*)(actions + ((size_t)e * TB_ + (size_t)t * B_ + am) * A_ + (k - L_));
      else
        av = *(const float4*)(xs + ((size_t)e * TB_ + (size_t)t * B_ + am) * D_ + (k - L_ - A_));
    }
    const float4 wv = *(const float4*)(W + (size_t)(k0 + bk) * L_ + (bn + bn4));
    __syncthreads();
    As[ak + 0][am] = av.x; As[ak + 1][am] = av.y;
    As[ak + 2][am] = av.z; As[ak + 3][am] = av.w;
    *(float4*)&Bs[bk][bn4] = wv;
    __syncthreads();
#pragma unroll
    for (int kk = 0; kk < 16; ++kk) {
      const float4 a4 = *(const float4*)&As[kk][tm];
      const float4 b4 = *(const float4*)&Bs[kk][tn];
      const float ar[4] = {a4.x, a4.y, a4.z, a4.w};
      const float br[4] = {b4.x, b4.y, b4.z, b4.w};
#pragma unroll
      for (int i = 0; i < 4; ++i)
#pragma unroll
        for (int j = 0; j < 4; ++j)
          acc[i][j] = fmaf(ar[i], br[j], acc[i][j]);
    }
  }
#pragma unroll
  for (int i = 0; i < 4; ++i) {
    const int m = tm + i;
    if (m < B_) {
#pragma unroll
      for (int j = 0; j < 4; ++j) {
        const float v = acc[i][j] + act_b[(size_t)e * L_ + bn + tn + j];
        zout[((size_t)e * B_ + m) * L_ + (bn + tn + j)] = v;
      }
    }
  }
}

// q = ctx @ qz0_w[e] + qz0_b[e]; KL reduce into logqp[e]; z0 for t==0 rows.
// grid (ceil(rows/16), E), block 256. Thread j owns column j (qm) and 256+j (ql).
__global__ __launch_bounds__(256)
void qkl_kernel(const float* __restrict__ ctx, int rows, int row_off, int ctx_estride,
                const float* __restrict__ qw, const float* __restrict__ qb,
                const float* __restrict__ pm, const float* __restrict__ pl,
                const float* __restrict__ eps0, float* __restrict__ z0,
                float* __restrict__ logqp) {
  __shared__ float cx[16][128];
  __shared__ float red[16];
  const int e = blockIdx.y;
  const int r0 = blockIdx.x * 16;
  const int tid = threadIdx.x;
  {
    const int r = tid >> 4, c = (tid & 15) * 8;
    float4 v0 = make_float4(0.f, 0.f, 0.f, 0.f), v1 = v0;
    if (r0 + r < rows) {
      const float* src = ctx + (size_t)e * ctx_estride + (size_t)(r0 + r) * C_ + c;
      v0 = *(const float4*)src;
      v1 = *(const float4*)(src + 4);
    }
    *(float4*)&cx[r][c] = v0;
    *(float4*)&cx[r][c + 4] = v1;
  }
  if (tid < 16) red[tid] = 0.f;
  __syncthreads();
  const int j = tid;
  const float* w = qw + (size_t)e * C_ * 512;
  float am_[16] = {};
  float al_[16] = {};
  for (int k0 = 0; k0 < C_; k0 += 4) {
    float wm[4], wl[4];
#pragma unroll
    for (int q = 0; q < 4; ++q) {
      wm[q] = w[(size_t)(k0 + q) * 512 + j];
      wl[q] = w[(size_t)(k0 + q) * 512 + 256 + j];
    }
#pragma unroll
    for (int r = 0; r < 16; ++r) {
      const float4 cv = *(const float4*)&cx[r][k0];
      const float cc[4] = {cv.x, cv.y, cv.z, cv.w};
#pragma unroll
      for (int q = 0; q < 4; ++q) {
        am_[r] = fmaf(cc[q], wm[q], am_[r]);
        al_[r] = fmaf(cc[q], wl[q], al_[r]);
      }
    }
  }
  const float qbm = qb[(size_t)e * 512 + j];
  const float qbl = qb[(size_t)e * 512 + 256 + j];
  const float pmv = pm[(size_t)e * L_ + j];
  const float plv = pl[(size_t)e * L_ + j];
  const float inv2e = 0.5f * expf(-2.f * plv);
#pragma unroll
  for (int r = 0; r < 16; ++r) {
    float kl = 0.f;
    if (r0 + r < rows) {
      const float qm_ = am_[r] + qbm;
      const float ql_ = al_[r] + qbl;
      const float dm = qm_ - pmv;
      kl = plv - ql_ + (expf(2.f * ql_) + dm * dm) * inv2e - 0.5f;
      const int gi = row_off + r0 + r;  // global row = t*B + b
      if (gi < B_) {                    // t == 0
        const size_t zi = ((size_t)e * B_ + gi) * L_ + j;
        z0[zi] = qm_ + expf(ql_) * eps0[zi];
      }
    }
    for (int off = 32; off; off >>= 1) kl += __shfl_xor(kl, off, 64);
    if ((tid & 63) == 0) atomicAdd(&red[r], kl);
  }
  __syncthreads();
  if (tid < 16 && r0 + tid < rows) atomicAdd(&logqp[e], red[tid] * (1.0f / B_));
}

// gv[r][l] = sum_h relu(z[r][l]*g_w1[l][h]+g_b1[l][h])*g_w2[l][h] + g_b2[l]
// grid (L, 8), block 64 (one wave); lane covers 16 h-elements.
__global__ __launch_bounds__(64)
void g_kernel(const float* __restrict__ z, const float* __restrict__ gw1,
              const float* __restrict__ gb1, const float* __restrict__ gw2,
              const float* __restrict__ gb2, float* __restrict__ gv) {
  const int l = blockIdx.x;
  const int r0 = blockIdx.y * 44;
  const int rend = (r0 + 44 < EB_) ? (r0 + 44) : EB_;
  const int lane = threadIdx.x;
  float w1[16], b1[16], w2[16];
#pragma unroll
  for (int i = 0; i < 16; ++i) {
    const int h = lane + i * 64;
    w1[i] = gw1[(size_t)l * H_ + h];
    b1[i] = gb1[(size_t)l * H_ + h];
    w2[i] = gw2[(size_t)l * H_ + h];
  }
  const float g2 = gb2[l];
  for (int r = r0; r < rend; ++r) {
    const float zv = z[(size_t)r * L_ + l];
    float acc = 0.f;
#pragma unroll
    for (int i = 0; i < 16; ++i) {
      float hh = fmaf(zv, w1[i], b1[i]);
      hh = fmaxf(hh, 0.f);
      acc = fmaf(hh, w2[i], acc);
    }
    for (int off = 32; off; off >>= 1) acc += __shfl_xor(acc, off, 64);
    if (lane == 0) gv[(size_t)r * L_ + l] = acc + g2;
  }
}

// fh2 = tanh(sum of 4 K-split partials + bias); layout [fb][r][n]
__global__ __launch_bounds__(256)
void fh2_combine(const float* __restrict__ p, const float* __restrict__ fb2,
                 const float* __restrict__ hb2, float* __restrict__ out) {
  const int idx = blockIdx.x * 256 + threadIdx.x;  // < 2*350*1024
  const int fb = idx / (EB_ * H_);
  const int rem = idx - fb * (EB_ * H_);
  const int n = rem & (H_ - 1);
  float v = fb ? hb2[n] : fb2[n];
#pragma unroll
  for (int s = 0; s < 4; ++s) v += p[(size_t)(fb * 4 + s) * EB_ * H_ + rem];
  out[idx] = tanhf(v);
}

// Epilogue: combine fh3 partials -> fv,hv; u=(fv-hv)/gv; lr; z_new -> zs_all[e][t]
__global__ __launch_bounds__(256)
void epi_kernel(const float* __restrict__ fvp, const float* __restrict__ fb3,
                const float* __restrict__ hb3, const float* __restrict__ gv,
                const float* __restrict__ z, const float* __restrict__ dw,
                float* __restrict__ zs_all, float* __restrict__ logqp, int t) {
  __shared__ float wsum[4];
  const int r = blockIdx.x;
  const int l = threadIdx.x;
  const int e = r / B_, b = r - e * B_;
  const size_t rl = (size_t)r * L_ + l;
  float fv = fb3[l], hv = hb3[l];
#pragma unroll
  for (int s = 0; s < 4; ++s) {
    fv += fvp[(size_t)s * EB_ * L_ + rl];
    hv += fvp[(size_t)(4 + s) * EB_ * L_ + rl];
  }
  const float gvv = gv[rl];
  const float u = (fv - hv) / gvv;
  float s_ = u * u;
  for (int off = 32; off; off >>= 1) s_ += __shfl_xor(s_, off, 64);
  if ((l & 63) == 0) wsum[l >> 6] = s_;
  __syncthreads();
  if (l == 0) {
    const float tot = wsum[0] + wsum[1] + wsum[2] + wsum[3];
    atomicAdd(&logqp[e], 0.5f * tot * 0.1f * (1.0f / B_));
  }
  const float znew = z[rl] + fv * 0.1f + gvv * (SQRTH * dw[(size_t)t * EB_ * L_ + rl]);
  zs_all[(((size_t)e * T_ + t) * B_ + b) * L_ + l] = znew;
}

__global__ void init_kernel(float* logqp) {
  if (threadIdx.x < E_) logqp[threadIdx.x] = 0.f;
}

extern "C" void kernel_launch(void* const* d_in, const int* in_sizes, int n_in,
                              void* d_out, int out_size, void* d_ws, size_t ws_size,
                              hipStream_t stream) {
  (void)in_sizes; (void)n_in; (void)out_size;
  const float* enc_w1 = (const float*)d_in[0];
  const float* enc_b1 = (const float*)d_in[1];
  const float* enc_w2 = (const float*)d_in[2];
  const float* enc_b2 = (const float*)d_in[3];
  const float* enc_w3 = (const float*)d_in[4];
  const float* enc_b3 = (const float*)d_in[5];
  const float* qz0_w  = (const float*)d_in[6];
  const float* qz0_b  = (const float*)d_in[7];
  const float* act_w  = (const float*)d_in[8];
  const float* act_b  = (const float*)d_in[9];
  const float* proj_w1 = (const float*)d_in[10];
  const float* proj_b1 = (const float*)d_in[11];
  const float* proj_w2 = (const float*)d_in[12];
  const float* proj_b2 = (const float*)d_in[13];
  const float* proj_w3 = (const float*)d_in[14];
  const float* proj_b3 = (const float*)d_in[15];
  const float* f_w1 = (const float*)d_in[16];
  const float* f_b1 = (const float*)d_in[17];
  const float* f_w2 = (const float*)d_in[18];
  const float* f_b2 = (const float*)d_in[19];
  const float* f_w3 = (const float*)d_in[20];
  const float* f_b3 = (const float*)d_in[21];
  const float* h_w1 = (const float*)d_in[22];
  const float* h_b1 = (const float*)d_in[23];
  const float* h_w2 = (const float*)d_in[24];
  const float* h_b2 = (const float*)d_in[25];
  const float* h_w3 = (const float*)d_in[26];
  const float* h_b3 = (const float*)d_in[27];
  const float* g_w1 = (const float*)d_in[28];
  const float* g_b1 = (const float*)d_in[29];
  const float* g_w2 = (const float*)d_in[30];
  const float* g_b2 = (const float*)d_in[31];
  const float* pz0_mean   = (const float*)d_in[32];
  const float* pz0_logstd = (const float*)d_in[33];
  const float* xs      = (const float*)d_in[34];
  const float* actions = (const float*)d_in[35];
  const float* eps_z0  = (const float*)d_in[36];
  const float* dw      = (const float*)d_in[37];

  float* out = (float*)d_out;
  float* logqp = out;      // 7 floats
  float* pred = out + E_;  // (E, T*B, D)

  float* w = (float*)d_ws;
  size_t off = 0;
  auto alloc = [&](size_t n) { float* p = w + off; off += n; return p; };
  float* zs_all = alloc((size_t)E_ * T_ * B_ * L_);  // z_new history (proj input)
  float* z0    = alloc((size_t)E_ * B_ * L_);
  float* zbuf  = alloc((size_t)EB_ * L_);
  float* fh1   = alloc((size_t)2 * EB_ * H_);
  float* fh2   = alloc((size_t)2 * EB_ * H_);
  float* fh2p  = alloc((size_t)8 * EB_ * H_);   // K-split partials
  float* fvhvp = alloc((size_t)8 * EB_ * L_);   // K-split partials
  float* gvb   = alloc((size_t)EB_ * L_);
  int CH = 1250;  // rows per phase-A / projector chunk (shrinks if ws is small)
  while (CH > 50 && (off + (size_t)E_ * CH * (2 * H_ + C_) + 1024) * sizeof(float) > ws_size)
    CH /= 5;
  float* bufA = alloc((size_t)E_ * CH * H_);
  float* bufB = alloc((size_t)E_ * CH * H_);
  float* bufC = alloc((size_t)E_ * CH * C_);

  init_kernel<<<dim3(1), dim3(64), 0, stream>>>(logqp);

  // ---- Phase A: encoder + q/KL (+ z0) over all T*B rows, chunked ----
  for (int c = 0; c < TB_; c += CH) {
    const int rows = (TB_ - c < CH) ? (TB_ - c) : CH;
    const int mt = (rows + 63) / 64;
    G8 g;
    for (int e = 0; e < E_; ++e) {
      g.A[e] = xs + ((size_t)e * TB_ + c) * D_;
      g.W[e] = enc_w1 + (size_t)e * D_ * H_;
      g.b[e] = enc_b1 + (size_t)e * H_;
      g.C[e] = bufA + (size_t)e * CH * H_;
    }
    gemm64<1><<<dim3(mt, H_ / 64, E_), 256, 0, stream>>>(g, rows, D_, D_, H_, H_);
    for (int e = 0; e < E_; ++e) {
      g.A[e] = bufA + (size_t)e * CH * H_;
      g.W[e] = enc_w2 + (size_t)e * H_ * H_;
      g.b[e] = enc_b2 + (size_t)e * H_;
      g.C[e] = bufB + (size_t)e * CH * H_;
    }
    gemm64<1><<<dim3(mt, H_ / 64, E_), 256, 0, stream>>>(g, rows, H_, H_, H_, H_);
    for (int e = 0; e < E_; ++e) {
      g.A[e] = bufB + (size_t)e * CH * H_;
      g.W[e] = enc_w3 + (size_t)e * H_ * C_;
      g.b[e] = enc_b3 + (size_t)e * C_;
      g.C[e] = bufC + (size_t)e * CH * C_;
    }
    gemm64<0><<<dim3(mt, C_ / 64, E_), 256, 0, stream>>>(g, rows, H_, H_, C_, C_);
    qkl_kernel<<<dim3((rows + 15) / 16, E_), 256, 0, stream>>>(
        bufC, rows, c, CH * C_, qz0_w, qz0_b, pz0_mean, pz0_logstd, eps_z0, z0, logqp);
  }

  // ---- Sequential scan over T ----
  for (int t = 0; t < T_; ++t) {
    const float* zin;
    int zes;
    if (t == 0) { zin = z0; zes = B_ * L_; }
    else { zin = zs_all + (size_t)(t - 1) * B_ * L_; zes = T_ * B_ * L_; }
    act_gemm<<<dim3(L_ / 64, E_), 256, 0, stream>>>(zin, zes, actions, xs, act_w, act_b, zbuf, t);
    G8 g;
    g.A[0] = zbuf; g.W[0] = f_w1; g.b[0] = f_b1; g.C[0] = fh1;
    g.A[1] = zbuf; g.W[1] = h_w1; g.b[1] = h_b1; g.C[1] = fh1 + (size_t)EB_ * H_;
    gemm64<1><<<dim3(6, H_ / 64, 2), 256, 0, stream>>>(g, EB_, L_, L_, H_, H_);
    for (int jj = 0; jj < 8; ++jj) {  // jj = fb*4 + s (K-split s of f/h layer 2)
      const int fb = jj >> 2, s = jj & 3;
      g.A[jj] = fh1 + (size_t)fb * EB_ * H_ + s * 256;
      g.W[jj] = (fb ? h_w2 : f_w2) + (size_t)s * 256 * H_;
      g.b[jj] = nullptr;
      g.C[jj] = fh2p + (size_t)jj * EB_ * H_;
    }
    gemm64<0><<<dim3(6, H_ / 64, 8), 256, 0, stream>>>(g, EB_, 256, H_, H_, H_);
    fh2_combine<<<dim3(2 * EB_ * H_ / 256), 256, 0, stream>>>(fh2p, f_b2, h_b2, fh2);
    for (int jj = 0; jj < 8; ++jj) {  // K-split of f/h layer 3
      const int fb = jj >> 2, s = jj & 3;
      g.A[jj] = fh2 + (size_t)fb * EB_ * H_ + s * 256;
      g.W[jj] = (fb ? h_w3 : f_w3) + (size_t)s * 256 * L_;
      g.b[jj] = nullptr;
      g.C[jj] = fvhvp + (size_t)jj * EB_ * L_;
    }
    gemm64<0><<<dim3(6, L_ / 64, 8), 256, 0, stream>>>(g, EB_, 256, H_, L_, L_);
    g_kernel<<<dim3(L_, 8), 64, 0, stream>>>(zbuf, g_w1, g_b1, g_w2, g_b2, gvb);
    epi_kernel<<<dim3(EB_), 256, 0, stream>>>(fvhvp, f_b3, h_b3, gvb, zbuf, dw, zs_all, logqp, t);
  }

  // ---- Projector over all stored z_new, chunked ----
  for (int c = 0; c < TB_; c += CH) {
    const int rows = (TB_ - c < CH) ? (TB_ - c) : CH;
    const int mt = (rows + 63) / 64;
    G8 g;
    for (int e = 0; e < E_; ++e) {
      g.A[e] = zs_all + ((size_t)e * T_ * B_ + c) * L_;
      g.W[e] = proj_w1 + (size_t)e * L_ * H_;
      g.b[e] = proj_b1 + (size_t)e * H_;
      g.C[e] = bufA + (size_t)e * CH * H_;
    }
    gemm64<2><<<dim3(mt, H_ / 64, E_), 256, 0, stream>>>(g, rows, L_, L_, H_, H_);
    for (int e = 0; e < E_; ++e) {
      g.A[e] = bufA + (size_t)e * CH * H_;
      g.W[e] = proj_w2 + (size_t)e * H_ * H_;
      g.b[e] = proj_b2 + (size_t)e * H_;
      g.C[e] = bufB + (size_t)e * CH * H_;
    }
    gemm64<2><<<dim3(mt, H_ / 64, E_), 256, 0, stream>>>(g, rows, H_, H_, H_, H_);
    for (int e = 0; e < E_; ++e) {
      g.A[e] = bufB + (size_t)e * CH * H_;
      g.W[e] = proj_w3 + (size_t)e * H_ * D_;
      g.b[e] = proj_b3 + (size_t)e * D_;
      g.C[e] = pred + ((size_t)e * TB_ + c) * D_;
    }
    gemm64<0><<<dim3(mt, D_ / 64, E_), 256, 0, stream>>>(g, rows, H_, H_, D_, D_);
  }
}

// Round 2
// 11164.197 us; speedup vs baseline: 1.4420x; 1.4420x over previous
//
#include <hip/hip_runtime.h>
#include <hip/hip_bf16.h>
#include <math.h>

#define E_ 7
#define B_ 50
#define T_ 100
#define D_ 128
#define A_ 32
#define L_ 256
#define H_ 1024
#define C_ 128
#define LAD_ 416
#define EB_ 350
#define TB_ 5000
#define SQRTH 0.31622776601683794f

typedef __attribute__((ext_vector_type(8))) short s8v;
typedef __attribute__((ext_vector_type(4))) float f32x4;
typedef __hip_bfloat16 bf16;

struct BG {
  const bf16* A[8];
  const bf16* W[8];     // pre-transposed [N][K] bf16
  const float* bias[8];
  float* Cf[8];
  bf16* Cb[8];
};

// ---------------- bf16 MFMA GEMM: C = ACT(A @ W^T' + b) ----------------
// A: [M,K] bf16 row-major (lda), W: [N,K] bf16 row-major (ldw = K stride).
// BN=128 fixed (grid.y = N/128), BM template (64|128), BK=64, 256 thr = 4 waves.
// K must be a multiple of 64. OUT: 0 = f32 store, 1 = bf16 store.
template<int BM, int ACT, int OUT>
__global__ __launch_bounds__(256)
void bgemm(BG g, int M, int K, int lda, int ldw, int ldc) {
  __shared__ short As[BM * 64];
  __shared__ short Ws[128 * 64];
  const short* Ap = (const short*)g.A[blockIdx.z];
  const short* Wp = (const short*)g.W[blockIdx.z];
  const int bm = blockIdx.x * BM, bn = blockIdx.y * 128;
  const int tid = threadIdx.x;
  const int wv = tid >> 6, lane = tid & 63;
  const int wm0 = (wv >> 1) * (BM / 2), wn0 = (wv & 1) * 64;
  const int l15 = lane & 15, l4 = lane >> 4;
  constexpr int FM = BM / 32;   // A-frags per wave (4 or 2)
  constexpr int AI = BM / 32;   // A staging iters
  f32x4 acc[FM][4] = {};
  for (int k0 = 0; k0 < K; k0 += 64) {
    s8v av[AI], wvv[4];
#pragma unroll
    for (int i = 0; i < AI; ++i) {
      const int c = tid + i * 256, r = c >> 3, ck = c & 7;
      s8v v = {};
      if (bm + r < M) v = *(const s8v*)(Ap + (size_t)(bm + r) * lda + k0 + ck * 8);
      av[i] = v;
    }
#pragma unroll
    for (int i = 0; i < 4; ++i) {
      const int c = tid + i * 256, r = c >> 3, ck = c & 7;
      wvv[i] = *(const s8v*)(Wp + (size_t)(bn + r) * ldw + k0 + ck * 8);
    }
    __syncthreads();
#pragma unroll
    for (int i = 0; i < AI; ++i) {
      const int c = tid + i * 256, r = c >> 3, ck = c & 7;
      *(s8v*)(As + r * 64 + ((ck ^ (r & 7)) << 3)) = av[i];
    }
#pragma unroll
    for (int i = 0; i < 4; ++i) {
      const int c = tid + i * 256, r = c >> 3, ck = c & 7;
      *(s8v*)(Ws + r * 64 + ((ck ^ (r & 7)) << 3)) = wvv[i];
    }
    __syncthreads();
#pragma unroll
    for (int ks = 0; ks < 2; ++ks) {
      s8v af[FM], bfr[4];
#pragma unroll
      for (int m = 0; m < FM; ++m) {
        const int r = wm0 + m * 16 + l15, ck = ks * 4 + l4;
        af[m] = *(const s8v*)(As + r * 64 + ((ck ^ (r & 7)) << 3));
      }
#pragma unroll
      for (int n = 0; n < 4; ++n) {
        const int r = wn0 + n * 16 + l15, ck = ks * 4 + l4;
        bfr[n] = *(const s8v*)(Ws + r * 64 + ((ck ^ (r & 7)) << 3));
      }
#pragma unroll
      for (int m = 0; m < FM; ++m)
#pragma unroll
        for (int n = 0; n < 4; ++n)
          acc[m][n] = __builtin_amdgcn_mfma_f32_16x16x32_bf16(af[m], bfr[n], acc[m][n], 0, 0, 0);
    }
    __syncthreads();
  }
  const float* bias = g.bias[blockIdx.z];
  float* Cf = g.Cf[blockIdx.z];
  bf16* Cb = g.Cb[blockIdx.z];
#pragma unroll
  for (int n = 0; n < 4; ++n) {
    const int col = bn + wn0 + n * 16 + l15;
    const float bv = bias ? bias[col] : 0.f;
#pragma unroll
    for (int m = 0; m < FM; ++m) {
#pragma unroll
      for (int j = 0; j < 4; ++j) {
        const int row = bm + wm0 + m * 16 + l4 * 4 + j;
        if (row < M) {
          float v = acc[m][n][j] + bv;
          if (ACT == 1) v = fmaxf(v, 0.f);
          if (ACT == 2) v = tanhf(v);
          if (OUT == 0) Cf[(size_t)row * ldc + col] = v;
          if (OUT == 1) Cb[(size_t)row * ldc + col] = __float2bfloat16(v);
        }
      }
    }
  }
}

// ---------------- weight convert+transpose: fp32 [K,N] -> bf16 [N,K] ----------------
__global__ __launch_bounds__(256)
void cvtT_kernel(const float* __restrict__ src, bf16* __restrict__ dst,
                 int K, int N, long ss, long ds) {
  __shared__ float t[32][33];
  src += (size_t)blockIdx.z * ss;
  dst += (size_t)blockIdx.z * ds;
  const int n0 = blockIdx.x * 32, k0 = blockIdx.y * 32;
  const int tx = threadIdx.x & 31, ty = threadIdx.x >> 5;  // 32 x 8
#pragma unroll
  for (int i = 0; i < 4; ++i)
    t[ty + 8 * i][tx] = src[(size_t)(k0 + ty + 8 * i) * N + n0 + tx];
  __syncthreads();
#pragma unroll
  for (int i = 0; i < 4; ++i)
    dst[(size_t)(n0 + ty + 8 * i) * K + k0 + tx] = __float2bfloat16(t[tx][ty + 8 * i]);
}

struct B4 { bf16 a, b, c, d; };
__global__ __launch_bounds__(256)
void cvt_kernel(const float* __restrict__ s, bf16* __restrict__ d, int n4) {
  const int i = blockIdx.x * 256 + threadIdx.x;
  if (i < n4) {
    const float4 v = ((const float4*)s)[i];
    B4 o = {__float2bfloat16(v.x), __float2bfloat16(v.y),
            __float2bfloat16(v.z), __float2bfloat16(v.w)};
    ((B4*)d)[i] = o;
  }
}

// ---------------- fp32 act GEMM (state path stays fp32) ----------------
// z = concat(z_in, a_t, x_t) @ act_w[e] + act_b[e]; writes fp32 + bf16
__global__ __launch_bounds__(256)
void act_gemm(const float* __restrict__ zin, int zin_estride,
              const float* __restrict__ actions, const float* __restrict__ xs,
              const float* __restrict__ act_w, const float* __restrict__ act_b,
              float* __restrict__ zout, bf16* __restrict__ zout_bf, int t) {
  __shared__ float As[16][68];
  __shared__ float Bs[16][64];
  const int tid = threadIdx.x;
  const int e = blockIdx.y;
  const int bn = blockIdx.x * 64;
  const int tm = (tid >> 4) << 2;
  const int tn = (tid & 15) << 2;
  const int am = tid >> 2;
  const int ak = (tid & 3) << 2;
  const int bk = tid >> 4;
  const int bn4 = (tid & 15) << 2;
  const float* W = act_w + (size_t)e * LAD_ * L_;
  const float* zin_e = zin + (size_t)e * zin_estride;
  float acc[4][4] = {};
  for (int k0 = 0; k0 < LAD_; k0 += 16) {
    float4 av = make_float4(0.f, 0.f, 0.f, 0.f);
    const int k = k0 + ak;
    if (am < B_) {
      if (k < L_)
        av = *(const float4*)(zin_e + (size_t)am * L_ + k);
      else if (k < L_ + A_)
        av = *(const float4*)(actions + ((size_t)e * TB_ + (size_t)t * B_ + am) * A_ + (k - L_));
      else
        av = *(const float4*)(xs + ((size_t)e * TB_ + (size_t)t * B_ + am) * D_ + (k - L_ - A_));
    }
    const float4 wv = *(const float4*)(W + (size_t)(k0 + bk) * L_ + (bn + bn4));
    __syncthreads();
    As[ak + 0][am] = av.x; As[ak + 1][am] = av.y;
    As[ak + 2][am] = av.z; As[ak + 3][am] = av.w;
    *(float4*)&Bs[bk][bn4] = wv;
    __syncthreads();
#pragma unroll
    for (int kk = 0; kk < 16; ++kk) {
      const float4 a4 = *(const float4*)&As[kk][tm];
      const float4 b4 = *(const float4*)&Bs[kk][tn];
      const float ar[4] = {a4.x, a4.y, a4.z, a4.w};
      const float br[4] = {b4.x, b4.y, b4.z, b4.w};
#pragma unroll
      for (int i = 0; i < 4; ++i)
#pragma unroll
        for (int j = 0; j < 4; ++j)
          acc[i][j] = fmaf(ar[i], br[j], acc[i][j]);
    }
  }
#pragma unroll
  for (int i = 0; i < 4; ++i) {
    const int m = tm + i;
    if (m < B_) {
#pragma unroll
      for (int j = 0; j < 4; ++j) {
        const float v = acc[i][j] + act_b[(size_t)e * L_ + bn + tn + j];
        const size_t idx = ((size_t)e * B_ + m) * L_ + (bn + tn + j);
        zout[idx] = v;
        zout_bf[idx] = __float2bfloat16(v);
      }
    }
  }
}

// ---------------- q/KL (+z0) ----------------
__global__ __launch_bounds__(256)
void qkl_kernel(const float* __restrict__ ctx, int rows, int row_off, int ctx_estride,
                const float* __restrict__ qw, const float* __restrict__ qb,
                const float* __restrict__ pm, const float* __restrict__ pl,
                const float* __restrict__ eps0, float* __restrict__ z0,
                float* __restrict__ logqp) {
  __shared__ float cx[16][128];
  __shared__ float red[16];
  const int e = blockIdx.y;
  const int r0 = blockIdx.x * 16;
  const int tid = threadIdx.x;
  {
    const int r = tid >> 4, c = (tid & 15) * 8;
    float4 v0 = make_float4(0.f, 0.f, 0.f, 0.f), v1 = v0;
    if (r0 + r < rows) {
      const float* src = ctx + (size_t)e * ctx_estride + (size_t)(r0 + r) * C_ + c;
      v0 = *(const float4*)src;
      v1 = *(const float4*)(src + 4);
    }
    *(float4*)&cx[r][c] = v0;
    *(float4*)&cx[r][c + 4] = v1;
  }
  if (tid < 16) red[tid] = 0.f;
  __syncthreads();
  const int j = tid;
  const float* w = qw + (size_t)e * C_ * 512;
  float am_[16] = {};
  float al_[16] = {};
  for (int k0 = 0; k0 < C_; k0 += 4) {
    float wm[4], wl[4];
#pragma unroll
    for (int q = 0; q < 4; ++q) {
      wm[q] = w[(size_t)(k0 + q) * 512 + j];
      wl[q] = w[(size_t)(k0 + q) * 512 + 256 + j];
    }
#pragma unroll
    for (int r = 0; r < 16; ++r) {
      const float4 cv = *(const float4*)&cx[r][k0];
      const float cc[4] = {cv.x, cv.y, cv.z, cv.w};
#pragma unroll
      for (int q = 0; q < 4; ++q) {
        am_[r] = fmaf(cc[q], wm[q], am_[r]);
        al_[r] = fmaf(cc[q], wl[q], al_[r]);
      }
    }
  }
  const float qbm = qb[(size_t)e * 512 + j];
  const float qbl = qb[(size_t)e * 512 + 256 + j];
  const float pmv = pm[(size_t)e * L_ + j];
  const float plv = pl[(size_t)e * L_ + j];
  const float inv2e = 0.5f * expf(-2.f * plv);
#pragma unroll
  for (int r = 0; r < 16; ++r) {
    float kl = 0.f;
    if (r0 + r < rows) {
      const float qm_ = am_[r] + qbm;
      const float ql_ = al_[r] + qbl;
      const float dm = qm_ - pmv;
      kl = plv - ql_ + (expf(2.f * ql_) + dm * dm) * inv2e - 0.5f;
      const int gi = row_off + r0 + r;
      if (gi < B_) {  // t == 0
        const size_t zi = ((size_t)e * B_ + gi) * L_ + j;
        z0[zi] = qm_ + expf(ql_) * eps0[zi];
      }
    }
    for (int off = 32; off; off >>= 1) kl += __shfl_xor(kl, off, 64);
    if ((tid & 63) == 0) atomicAdd(&red[r], kl);
  }
  __syncthreads();
  if (tid < 16 && r0 + tid < rows) atomicAdd(&logqp[e], red[tid] * (1.0f / B_));
}

// ---------------- g function ----------------
__global__ __launch_bounds__(64)
void g_kernel(const float* __restrict__ z, const float* __restrict__ gw1,
              const float* __restrict__ gb1, const float* __restrict__ gw2,
              const float* __restrict__ gb2, float* __restrict__ gv) {
  const int l = blockIdx.x;
  const int r0 = blockIdx.y * 44;
  const int rend = (r0 + 44 < EB_) ? (r0 + 44) : EB_;
  const int lane = threadIdx.x;
  float w1[16], b1[16], w2[16];
#pragma unroll
  for (int i = 0; i < 16; ++i) {
    const int h = lane + i * 64;
    w1[i] = gw1[(size_t)l * H_ + h];
    b1[i] = gb1[(size_t)l * H_ + h];
    w2[i] = gw2[(size_t)l * H_ + h];
  }
  const float g2 = gb2[l];
  for (int r = r0; r < rend; ++r) {
    const float zv = z[(size_t)r * L_ + l];
    float acc = 0.f;
#pragma unroll
    for (int i = 0; i < 16; ++i) {
      float hh = fmaf(zv, w1[i], b1[i]);
      hh = fmaxf(hh, 0.f);
      acc = fmaf(hh, w2[i], acc);
    }
    for (int off = 32; off; off >>= 1) acc += __shfl_xor(acc, off, 64);
    if (lane == 0) gv[(size_t)r * L_ + l] = acc + g2;
  }
}

// ---------------- epilogue ----------------
__global__ __launch_bounds__(256)
void epi_kernel(const float* __restrict__ fvp, const float* __restrict__ fb3,
                const float* __restrict__ hb3, const float* __restrict__ gv,
                const float* __restrict__ z, const float* __restrict__ dw,
                float* __restrict__ zs_all, bf16* __restrict__ zs_bf,
                float* __restrict__ logqp, int t) {
  __shared__ float wsum[4];
  const int r = blockIdx.x;
  const int l = threadIdx.x;
  const int e = r / B_, b = r - e * B_;
  const size_t rl = (size_t)r * L_ + l;
  float fv = fb3[l], hv = hb3[l];
#pragma unroll
  for (int s = 0; s < 4; ++s) {
    fv += fvp[(size_t)s * EB_ * L_ + rl];
    hv += fvp[(size_t)(4 + s) * EB_ * L_ + rl];
  }
  const float gvv = gv[rl];
  const float u = (fv - hv) / gvv;
  float s_ = u * u;
  for (int off = 32; off; off >>= 1) s_ += __shfl_xor(s_, off, 64);
  if ((l & 63) == 0) wsum[l >> 6] = s_;
  __syncthreads();
  if (l == 0) {
    const float tot = wsum[0] + wsum[1] + wsum[2] + wsum[3];
    atomicAdd(&logqp[e], 0.5f * tot * 0.1f * (1.0f / B_));
  }
  const float znew = z[rl] + fv * 0.1f + gvv * (SQRTH * dw[(size_t)t * EB_ * L_ + rl]);
  const size_t oi = (((size_t)e * T_ + t) * B_ + b) * L_ + l;
  zs_all[oi] = znew;
  zs_bf[oi] = __float2bfloat16(znew);
}

__global__ void init_kernel(float* logqp) {
  if (threadIdx.x < E_) logqp[threadIdx.x] = 0.f;
}

extern "C" void kernel_launch(void* const* d_in, const int* in_sizes, int n_in,
                              void* d_out, int out_size, void* d_ws, size_t ws_size,
                              hipStream_t stream) {
  (void)in_sizes; (void)n_in; (void)out_size;
  const float* enc_w1 = (const float*)d_in[0];
  const float* enc_b1 = (const float*)d_in[1];
  const float* enc_w2 = (const float*)d_in[2];
  const float* enc_b2 = (const float*)d_in[3];
  const float* enc_w3 = (const float*)d_in[4];
  const float* enc_b3 = (const float*)d_in[5];
  const float* qz0_w  = (const float*)d_in[6];
  const float* qz0_b  = (const float*)d_in[7];
  const float* act_w  = (const float*)d_in[8];
  const float* act_b  = (const float*)d_in[9];
  const float* proj_w1 = (const float*)d_in[10];
  const float* proj_b1 = (const float*)d_in[11];
  const float* proj_w2 = (const float*)d_in[12];
  const float* proj_b2 = (const float*)d_in[13];
  const float* proj_w3 = (const float*)d_in[14];
  const float* proj_b3 = (const float*)d_in[15];
  const float* f_w1 = (const float*)d_in[16];
  const float* f_b1 = (const float*)d_in[17];
  const float* f_w2 = (const float*)d_in[18];
  const float* f_b2 = (const float*)d_in[19];
  const float* f_w3 = (const float*)d_in[20];
  const float* f_b3 = (const float*)d_in[21];
  const float* h_w1 = (const float*)d_in[22];
  const float* h_b1 = (const float*)d_in[23];
  const float* h_w2 = (const float*)d_in[24];
  const float* h_b2 = (const float*)d_in[25];
  const float* h_w3 = (const float*)d_in[26];
  const float* h_b3 = (const float*)d_in[27];
  const float* g_w1 = (const float*)d_in[28];
  const float* g_b1 = (const float*)d_in[29];
  const float* g_w2 = (const float*)d_in[30];
  const float* g_b2 = (const float*)d_in[31];
  const float* pz0_mean   = (const float*)d_in[32];
  const float* pz0_logstd = (const float*)d_in[33];
  const float* xs      = (const float*)d_in[34];
  const float* actions = (const float*)d_in[35];
  const float* eps_z0  = (const float*)d_in[36];
  const float* dw      = (const float*)d_in[37];

  float* out = (float*)d_out;
  float* logqp = out;      // 7 floats
  float* pred = out + E_;  // (E, T*B, D)

  char* base = (char*)d_ws;
  size_t off = 0;
  auto alloc = [&](size_t bytes) {
    void* p = base + off;
    off = (off + bytes + 255) & ~(size_t)255;
    return p;
  };
  float* zs_all = (float*)alloc((size_t)E_ * T_ * B_ * L_ * 4);
  bf16* zs_bf   = (bf16*)alloc((size_t)E_ * T_ * B_ * L_ * 2);
  float* z0     = (float*)alloc((size_t)E_ * B_ * L_ * 4);
  float* zbuf   = (float*)alloc((size_t)EB_ * L_ * 4);
  bf16* zbuf_bf = (bf16*)alloc((size_t)EB_ * L_ * 2);
  bf16* fh1     = (bf16*)alloc((size_t)2 * EB_ * H_ * 2);
  bf16* fh2     = (bf16*)alloc((size_t)2 * EB_ * H_ * 2);
  float* fvhvp  = (float*)alloc((size_t)8 * EB_ * L_ * 4);
  float* gvb    = (float*)alloc((size_t)EB_ * L_ * 4);
  bf16* xs_bf   = (bf16*)alloc((size_t)E_ * TB_ * D_ * 2);
  bf16* ew1T = (bf16*)alloc((size_t)E_ * D_ * H_ * 2);
  bf16* ew2T = (bf16*)alloc((size_t)E_ * H_ * H_ * 2);
  bf16* ew3T = (bf16*)alloc((size_t)E_ * H_ * C_ * 2);
  bf16* pw1T = (bf16*)alloc((size_t)E_ * L_ * H_ * 2);
  bf16* pw2T = (bf16*)alloc((size_t)E_ * H_ * H_ * 2);
  bf16* pw3T = (bf16*)alloc((size_t)E_ * H_ * D_ * 2);
  bf16* fw1T = (bf16*)alloc((size_t)L_ * H_ * 2);
  bf16* fw2T = (bf16*)alloc((size_t)H_ * H_ * 2);
  bf16* fw3T = (bf16*)alloc((size_t)H_ * L_ * 2);
  bf16* hw1T = (bf16*)alloc((size_t)L_ * H_ * 2);
  bf16* hw2T = (bf16*)alloc((size_t)H_ * H_ * 2);
  bf16* hw3T = (bf16*)alloc((size_t)H_ * L_ * 2);
  // chunk buffers sized from remaining ws
  const size_t per_row = (size_t)E_ * (H_ * 2 * 2 + C_ * 4);  // bufA+bufB bf16, bufC f32
  size_t remain = (ws_size > off + 4096) ? (ws_size - off - 4096) : 0;
  int CH = (int)(remain / per_row);
  if (CH > 2500) CH = 2500;
  if (CH < 64) CH = 64;  // last resort; ws should be plenty
  bf16* bufA = (bf16*)alloc((size_t)E_ * CH * H_ * 2);
  bf16* bufB = (bf16*)alloc((size_t)E_ * CH * H_ * 2);
  float* bufC = (float*)alloc((size_t)E_ * CH * C_ * 4);

  init_kernel<<<dim3(1), dim3(64), 0, stream>>>(logqp);

  // ---- weight conversions (per replay; cheap) ----
  const dim3 cb(256);
  cvt_kernel<<<dim3((E_ * TB_ * D_ / 4 + 255) / 256), cb, 0, stream>>>(xs, xs_bf, E_ * TB_ * D_ / 4);
  cvtT_kernel<<<dim3(H_ / 32, D_ / 32, E_), cb, 0, stream>>>(enc_w1, ew1T, D_, H_, (long)D_ * H_, (long)D_ * H_);
  cvtT_kernel<<<dim3(H_ / 32, H_ / 32, E_), cb, 0, stream>>>(enc_w2, ew2T, H_, H_, (long)H_ * H_, (long)H_ * H_);
  cvtT_kernel<<<dim3(C_ / 32, H_ / 32, E_), cb, 0, stream>>>(enc_w3, ew3T, H_, C_, (long)H_ * C_, (long)H_ * C_);
  cvtT_kernel<<<dim3(H_ / 32, L_ / 32, E_), cb, 0, stream>>>(proj_w1, pw1T, L_, H_, (long)L_ * H_, (long)L_ * H_);
  cvtT_kernel<<<dim3(H_ / 32, H_ / 32, E_), cb, 0, stream>>>(proj_w2, pw2T, H_, H_, (long)H_ * H_, (long)H_ * H_);
  cvtT_kernel<<<dim3(D_ / 32, H_ / 32, E_), cb, 0, stream>>>(proj_w3, pw3T, H_, D_, (long)H_ * D_, (long)H_ * D_);
  cvtT_kernel<<<dim3(H_ / 32, L_ / 32, 1), cb, 0, stream>>>(f_w1, fw1T, L_, H_, 0, 0);
  cvtT_kernel<<<dim3(H_ / 32, H_ / 32, 1), cb, 0, stream>>>(f_w2, fw2T, H_, H_, 0, 0);
  cvtT_kernel<<<dim3(L_ / 32, H_ / 32, 1), cb, 0, stream>>>(f_w3, fw3T, H_, L_, 0, 0);
  cvtT_kernel<<<dim3(H_ / 32, L_ / 32, 1), cb, 0, stream>>>(h_w1, hw1T, L_, H_, 0, 0);
  cvtT_kernel<<<dim3(H_ / 32, H_ / 32, 1), cb, 0, stream>>>(h_w2, hw2T, H_, H_, 0, 0);
  cvtT_kernel<<<dim3(L_ / 32, H_ / 32, 1), cb, 0, stream>>>(h_w3, hw3T, H_, L_, 0, 0);

  BG g;
  // ---- Phase A: encoder + q/KL (+z0) ----
  for (int c = 0; c < TB_; c += CH) {
    const int rows = (TB_ - c < CH) ? (TB_ - c) : CH;
    const int mt = (rows + 127) / 128;
    for (int e = 0; e < E_; ++e) {
      g.A[e] = xs_bf + ((size_t)e * TB_ + c) * D_;
      g.W[e] = ew1T + (size_t)e * D_ * H_;
      g.bias[e] = enc_b1 + (size_t)e * H_;
      g.Cb[e] = bufA + (size_t)e * CH * H_;
    }
    bgemm<128, 1, 1><<<dim3(mt, H_ / 128, E_), 256, 0, stream>>>(g, rows, D_, D_, D_, H_);
    for (int e = 0; e < E_; ++e) {
      g.A[e] = bufA + (size_t)e * CH * H_;
      g.W[e] = ew2T + (size_t)e * H_ * H_;
      g.bias[e] = enc_b2 + (size_t)e * H_;
      g.Cb[e] = bufB + (size_t)e * CH * H_;
    }
    bgemm<128, 1, 1><<<dim3(mt, H_ / 128, E_), 256, 0, stream>>>(g, rows, H_, H_, H_, H_);
    for (int e = 0; e < E_; ++e) {
      g.A[e] = bufB + (size_t)e * CH * H_;
      g.W[e] = ew3T + (size_t)e * H_ * C_;
      g.bias[e] = enc_b3 + (size_t)e * C_;
      g.Cf[e] = bufC + (size_t)e * CH * C_;
    }
    bgemm<128, 0, 0><<<dim3(mt, C_ / 128, E_), 256, 0, stream>>>(g, rows, H_, H_, H_, C_);
    qkl_kernel<<<dim3((rows + 15) / 16, E_), 256, 0, stream>>>(
        bufC, rows, c, CH * C_, qz0_w, qz0_b, pz0_mean, pz0_logstd, eps_z0, z0, logqp);
  }

  // ---- Sequential scan ----
  for (int t = 0; t < T_; ++t) {
    const float* zin;
    int zes;
    if (t == 0) { zin = z0; zes = B_ * L_; }
    else { zin = zs_all + (size_t)(t - 1) * B_ * L_; zes = T_ * B_ * L_; }
    act_gemm<<<dim3(L_ / 64, E_), 256, 0, stream>>>(zin, zes, actions, xs, act_w, act_b,
                                                    zbuf, zbuf_bf, t);
    // L1: relu(z @ w1) for f,h
    g.A[0] = zbuf_bf; g.W[0] = fw1T; g.bias[0] = f_b1; g.Cb[0] = fh1;
    g.A[1] = zbuf_bf; g.W[1] = hw1T; g.bias[1] = h_b1; g.Cb[1] = fh1 + (size_t)EB_ * H_;
    bgemm<64, 1, 1><<<dim3(6, H_ / 128, 2), 256, 0, stream>>>(g, EB_, L_, L_, L_, H_);
    // L2: tanh(a1 @ w2)
    g.A[0] = fh1; g.W[0] = fw2T; g.bias[0] = f_b2; g.Cb[0] = fh2;
    g.A[1] = fh1 + (size_t)EB_ * H_; g.W[1] = hw2T; g.bias[1] = h_b2;
    g.Cb[1] = fh2 + (size_t)EB_ * H_;
    bgemm<64, 2, 1><<<dim3(6, H_ / 128, 2), 256, 0, stream>>>(g, EB_, H_, H_, H_, H_);
    // L3: split-K=4 partials (f: jj 0..3, h: jj 4..7)
    for (int jj = 0; jj < 8; ++jj) {
      const int fb = jj >> 2, s = jj & 3;
      g.A[jj] = fh2 + (size_t)fb * EB_ * H_ + s * 256;
      g.W[jj] = (fb ? hw3T : fw3T) + s * 256;
      g.bias[jj] = nullptr;
      g.Cf[jj] = fvhvp + (size_t)jj * EB_ * L_;
    }
    bgemm<64, 0, 0><<<dim3(6, L_ / 128, 8), 256, 0, stream>>>(g, EB_, 256, H_, H_, L_);
    g_kernel<<<dim3(L_, 8), 64, 0, stream>>>(zbuf, g_w1, g_b1, g_w2, g_b2, gvb);
    epi_kernel<<<dim3(EB_), 256, 0, stream>>>(fvhvp, f_b3, h_b3, gvb, zbuf, dw,
                                              zs_all, zs_bf, logqp, t);
  }

  // ---- Projector ----
  for (int c = 0; c < TB_; c += CH) {
    const int rows = (TB_ - c < CH) ? (TB_ - c) : CH;
    const int mt = (rows + 127) / 128;
    for (int e = 0; e < E_; ++e) {
      g.A[e] = zs_bf + ((size_t)e * T_ * B_ + c) * L_;
      g.W[e] = pw1T + (size_t)e * L_ * H_;
      g.bias[e] = proj_b1 + (size_t)e * H_;
      g.Cb[e] = bufA + (size_t)e * CH * H_;
    }
    bgemm<128, 2, 1><<<dim3(mt, H_ / 128, E_), 256, 0, stream>>>(g, rows, L_, L_, L_, H_);
    for (int e = 0; e < E_; ++e) {
      g.A[e] = bufA + (size_t)e * CH * H_;
      g.W[e] = pw2T + (size_t)e * H_ * H_;
      g.bias[e] = proj_b2 + (size_t)e * H_;
      g.Cb[e] = bufB + (size_t)e * CH * H_;
    }
    bgemm<128, 2, 1><<<dim3(mt, H_ / 128, E_), 256, 0, stream>>>(g, rows, H_, H_, H_, H_);
    for (int e = 0; e < E_; ++e) {
      g.A[e] = bufB + (size_t)e * CH * H_;
      g.W[e] = pw3T + (size_t)e * H_ * D_;
      g.bias[e] = proj_b3 + (size_t)e * D_;
      g.Cf[e] = pred + ((size_t)e * TB_ + c) * D_;
    }
    bgemm<128, 0, 0><<<dim3(mt, D_ / 128, E_), 256, 0, stream>>>(g, rows, H_, H_, H_, D_);
  }
}